// Round 7
// baseline (272.988 us; speedup 1.0000x reference)
//
#include <hip/hip_runtime.h>
#include <cstdint>
#include <cstddef>

// x[B=32, T=4096, N=256] fp32 -> z same shape.
// Refractory scan: spike at step t iff x>0 and t >= na; then na = t+6.
//
// R7: ZERO global sync, single kernel. R6 analysis: 8-hop serial chain
// costs ~30us of the 73us kernel (h ~ 4-5us/hop cross-XCD). Fix: block =
// (batch, N-slice of 16 chains) owning the FULL T=4096 chain -> 512
// independent blocks (2/CU), no msg/atomics/poison. Per-chunk entry->exit
// maps composed in-block via 7-round Hillis-Steele scan over comp6 in LDS.
// z stores nontemporal so the output stream doesn't evict x from L3.
#define BB 32
#define TT 4096
#define NNV 64      // float4 groups per row (N=256)
#define SLW 4       // slice width in float4 groups (16 chains per block)
#define NSL 16      // slices per row = NNV/SLW
#define CC 32       // steps per chunk (one u32 bitmask per chain)
#define NCK 128     // chunks per chain in block = TT/CC
#define NCHB 16     // chains per block = SLW*4

typedef float f32x4 __attribute__((ext_vector_type(4)));

// Compose 6-nibble maps: h = "f then g", h[e] = g[f[e]].
__device__ __forceinline__ uint32_t comp6(uint32_t f, uint32_t g) {
    uint32_t h = 0;
    #pragma unroll
    for (int e = 0; e < 6; ++e) {
        const uint32_t fe = (f >> (4 * e)) & 0xFu;
        h |= ((g >> (4 * fe)) & 0xFu) << (4 * e);
    }
    return h;
}

// Per-chunk entry->exit table from a 32-step sign bitmask.
// <=6 spikes per 32 steps (each advances na by 6): 6 branchless ctz iters.
__device__ __forceinline__ uint32_t tbl_from_mask(uint32_t m) {
    uint32_t tbl = 0;
    #pragma unroll
    for (int e = 0; e < 6; ++e) {
        int na = e;
        #pragma unroll
        for (int it = 0; it < 6; ++it) {
            const uint32_t r = (na < 32) ? (m >> na) : 0u;
            const int t = na + (r ? __builtin_ctz(r) : 0);
            na = r ? (t + 6) : na;
        }
        const int q = na > CC ? na - CC : 0;   // exit state in [0,5]
        tbl |= (uint32_t)q << (4 * e);
    }
    return tbl;
}

__global__ __launch_bounds__(512, 4) void refrac(const float* __restrict__ x,
                                                 float* __restrict__ z) {
    const int tid = threadIdx.x;
    const int b  = blockIdx.x >> 4;        // batch
    const int ns = blockIdx.x & (NSL - 1); // N-slice
    const int n4r = tid & (SLW - 1);       // float4 group within slice
    const int ck  = tid >> 2;              // chunk index 0..127

    const float4* __restrict__ xv = reinterpret_cast<const float4*>(x)
        + ((size_t)b * TT + (size_t)ck * CC) * NNV + ns * SLW + n4r;

    // --- Phase 1: load + sign-bit extraction (32 steps per thread) ---
    uint32_t cur[4] = {0u, 0u, 0u, 0u};
    #pragma unroll
    for (int jb = 0; jb < CC; jb += 8) {
        float4 buf[8];
        #pragma unroll
        for (int u = 0; u < 8; ++u)
            buf[u] = xv[(size_t)(jb + u) * NNV];
        #pragma unroll
        for (int u = 0; u < 8; ++u) {
            const int j = jb + u;
            cur[0] |= (buf[u].x > 0.0f) ? (1u << j) : 0u;
            cur[1] |= (buf[u].y > 0.0f) ? (1u << j) : 0u;
            cur[2] |= (buf[u].z > 0.0f) ? (1u << j) : 0u;
            cur[3] |= (buf[u].w > 0.0f) ? (1u << j) : 0u;
        }
    }

    // --- Phase 2: in-block parallel prefix over chunk maps (comp6) ---
    __shared__ uint32_t sc[2][NCK][NCHB];   // ping-pong, 2 x 8 KB
    #pragma unroll
    for (int c = 0; c < 4; ++c)
        sc[0][ck][n4r * 4 + c] = tbl_from_mask(cur[c]);
    __syncthreads();

    int sb = 0;
    #pragma unroll
    for (int o = 1; o < NCK; o <<= 1) {     // 7 rounds
        #pragma unroll
        for (int it = 0; it < (NCK * NCHB) / 512; ++it) {  // 4 items/thread
            const int i  = tid + it * 512;
            const int ic = i >> 4;          // chunk
            const int ch = i & (NCHB - 1);  // chain
            uint32_t v = sc[sb][ic][ch];
            if (ic >= o) v = comp6(sc[sb][ic - o][ch], v);
            sc[sb ^ 1][ic][ch] = v;
        }
        __syncthreads();
        sb ^= 1;
    }
    // sc[sb][i][ch] = m[0] o ... o m[i] (inclusive prefix, "then" order).

    // --- Phase 3: entry state + spike walk + nontemporal emit ---
    uint32_t spk[4];
    #pragma unroll
    for (int c = 0; c < 4; ++c) {
        const int e0 = (ck == 0) ? 0
            : (int)(sc[sb][ck - 1][n4r * 4 + c] & 0xFu);
        const uint32_t m = cur[c];
        int na = e0;
        uint32_t s = 0;
        #pragma unroll
        for (int it = 0; it < 6; ++it) {
            const uint32_t r = (na < 32) ? (m >> na) : 0u;
            const int t = na + (r ? __builtin_ctz(r) : 0);
            s |= r ? (1u << (t & 31)) : 0u;   // t < 32 whenever r != 0
            na = r ? (t + 6) : na;
        }
        spk[c] = s;
    }

    f32x4* __restrict__ zv = reinterpret_cast<f32x4*>(z)
        + ((size_t)b * TT + (size_t)ck * CC) * NNV + ns * SLW + n4r;

    #pragma unroll
    for (int j = 0; j < CC; ++j) {
        f32x4 o = { ((spk[0] >> j) & 1u) ? 1.0f : 0.0f,
                    ((spk[1] >> j) & 1u) ? 1.0f : 0.0f,
                    ((spk[2] >> j) & 1u) ? 1.0f : 0.0f,
                    ((spk[3] >> j) & 1u) ? 1.0f : 0.0f };
        __builtin_nontemporal_store(o, &zv[(size_t)j * NNV]);
    }
}

extern "C" void kernel_launch(void* const* d_in, const int* in_sizes, int n_in,
                              void* d_out, int out_size, void* d_ws, size_t ws_size,
                              hipStream_t stream) {
    const float* x = (const float*)d_in[0];
    float* z = (float*)d_out;
    (void)d_ws; (void)ws_size;   // no workspace, no poison, no atomics

    refrac<<<dim3(BB * NSL), 512, 0, stream>>>(x, z);
}

// Round 8
// 260.211 us; speedup vs baseline: 1.0491x; 1.0491x over previous
//
#include <hip/hip_runtime.h>
#include <cstdint>
#include <cstddef>

// x[B=32, T=4096, N=256] fp32 -> z same shape.
// Refractory scan: spike at step t iff x>0 and t >= na; then na = t+6.
//
// R8 = R7 (zero-sync, block owns full T chain) with the read geometry
// fixed: R7's 64 B slice fetched half-lines (FETCH 66->131 MB, the whole
// regression). Slice width now 8 float4 = 128 B = one cache line; grid
// 256 blocks (1/CU) x 1024 threads; wave reads 8 full lines per instr.
// Scan LDS padded (stride 33) to kill the 98K bank conflicts.
#define BB 32
#define TT 4096
#define NNV 64      // float4 groups per row (N=256)
#define SLW 8       // slice width in float4 groups = 128 B = 1 line
#define NSL 8       // slices per row = NNV/SLW
#define CC 32       // steps per chunk (one u32 bitmask per chain)
#define NCK 128     // chunks per chain in block = TT/CC
#define NCHB 32     // chains per block = SLW*4
#define PAD 33      // LDS row stride (banks spread)

typedef float f32x4 __attribute__((ext_vector_type(4)));

// Compose 6-nibble maps: h = "f then g", h[e] = g[f[e]].
__device__ __forceinline__ uint32_t comp6(uint32_t f, uint32_t g) {
    uint32_t h = 0;
    #pragma unroll
    for (int e = 0; e < 6; ++e) {
        const uint32_t fe = (f >> (4 * e)) & 0xFu;
        h |= ((g >> (4 * fe)) & 0xFu) << (4 * e);
    }
    return h;
}

// Per-chunk entry->exit table from a 32-step sign bitmask.
// <=6 spikes per 32 steps (each advances na by 6): 6 branchless ctz iters.
__device__ __forceinline__ uint32_t tbl_from_mask(uint32_t m) {
    uint32_t tbl = 0;
    #pragma unroll
    for (int e = 0; e < 6; ++e) {
        int na = e;
        #pragma unroll
        for (int it = 0; it < 6; ++it) {
            const uint32_t r = (na < 32) ? (m >> na) : 0u;
            const int t = na + (r ? __builtin_ctz(r) : 0);
            na = r ? (t + 6) : na;
        }
        const int q = na > CC ? na - CC : 0;   // exit state in [0,5]
        tbl |= (uint32_t)q << (4 * e);
    }
    return tbl;
}

__global__ __launch_bounds__(1024, 4) void refrac(const float* __restrict__ x,
                                                  float* __restrict__ z) {
    const int tid = threadIdx.x;
    const int b  = blockIdx.x >> 3;        // batch
    const int ns = blockIdx.x & (NSL - 1); // N-slice (128 B aligned)
    const int n4r = tid & (SLW - 1);       // float4 group within slice
    const int ck  = tid >> 3;              // chunk index 0..127

    const float4* __restrict__ xv = reinterpret_cast<const float4*>(x)
        + ((size_t)b * TT + (size_t)ck * CC) * NNV + ns * SLW + n4r;

    // --- Phase 1: load + sign-bit extraction (32 steps per thread) ---
    uint32_t cur[4] = {0u, 0u, 0u, 0u};
    #pragma unroll
    for (int jb = 0; jb < CC; jb += 8) {
        float4 buf[8];
        #pragma unroll
        for (int u = 0; u < 8; ++u)
            buf[u] = xv[(size_t)(jb + u) * NNV];
        #pragma unroll
        for (int u = 0; u < 8; ++u) {
            const int j = jb + u;
            cur[0] |= (buf[u].x > 0.0f) ? (1u << j) : 0u;
            cur[1] |= (buf[u].y > 0.0f) ? (1u << j) : 0u;
            cur[2] |= (buf[u].z > 0.0f) ? (1u << j) : 0u;
            cur[3] |= (buf[u].w > 0.0f) ? (1u << j) : 0u;
        }
    }

    // --- Phase 2: in-block parallel prefix over chunk maps (comp6) ---
    __shared__ uint32_t sc[2][NCK][PAD];    // ping-pong, ~33 KB
    #pragma unroll
    for (int c = 0; c < 4; ++c)
        sc[0][ck][n4r * 4 + c] = tbl_from_mask(cur[c]);
    __syncthreads();

    int sb = 0;
    #pragma unroll
    for (int o = 1; o < NCK; o <<= 1) {     // 7 rounds
        #pragma unroll
        for (int it = 0; it < (NCK * NCHB) / 1024; ++it) {  // 4 items/thread
            const int i  = tid + it * 1024;
            const int ic = i >> 5;          // chunk
            const int ch = i & (NCHB - 1);  // chain
            uint32_t v = sc[sb][ic][ch];
            if (ic >= o) v = comp6(sc[sb][ic - o][ch], v);
            sc[sb ^ 1][ic][ch] = v;
        }
        __syncthreads();
        sb ^= 1;
    }
    // sc[sb][i][ch] = m[0] o ... o m[i] (inclusive prefix, "then" order).

    // --- Phase 3: entry state + spike walk + nontemporal emit ---
    uint32_t spk[4];
    #pragma unroll
    for (int c = 0; c < 4; ++c) {
        const int e0 = (ck == 0) ? 0
            : (int)(sc[sb][ck - 1][n4r * 4 + c] & 0xFu);
        const uint32_t m = cur[c];
        int na = e0;
        uint32_t s = 0;
        #pragma unroll
        for (int it = 0; it < 6; ++it) {
            const uint32_t r = (na < 32) ? (m >> na) : 0u;
            const int t = na + (r ? __builtin_ctz(r) : 0);
            s |= r ? (1u << (t & 31)) : 0u;   // t < 32 whenever r != 0
            na = r ? (t + 6) : na;
        }
        spk[c] = s;
    }

    f32x4* __restrict__ zv = reinterpret_cast<f32x4*>(z)
        + ((size_t)b * TT + (size_t)ck * CC) * NNV + ns * SLW + n4r;

    #pragma unroll
    for (int j = 0; j < CC; ++j) {
        f32x4 o = { ((spk[0] >> j) & 1u) ? 1.0f : 0.0f,
                    ((spk[1] >> j) & 1u) ? 1.0f : 0.0f,
                    ((spk[2] >> j) & 1u) ? 1.0f : 0.0f,
                    ((spk[3] >> j) & 1u) ? 1.0f : 0.0f };
        __builtin_nontemporal_store(o, &zv[(size_t)j * NNV]);
    }
}

extern "C" void kernel_launch(void* const* d_in, const int* in_sizes, int n_in,
                              void* d_out, int out_size, void* d_ws, size_t ws_size,
                              hipStream_t stream) {
    const float* x = (const float*)d_in[0];
    float* z = (float*)d_out;
    (void)d_ws; (void)ws_size;   // no workspace, no poison, no atomics

    refrac<<<dim3(BB * NSL), 1024, 0, stream>>>(x, z);
}

// Round 9
// 235.441 us; speedup vs baseline: 1.1595x; 1.1052x over previous
//
#include <hip/hip_runtime.h>
#include <cstdint>
#include <cstddef>

// x[B=32, T=4096, N=256] fp32 -> z same shape.
// Refractory scan: spike at step t iff x>0 and t >= na; then na = t+6.
// Entry state q==k <=> first k steps of chunk blocked. q in [0,5].
//
// R9 = R6's proven geometry (block=(b,pg), contiguous 1 KB wave spans,
// plain stores; R8 proved scattered-128B wave patterns halve DRAM BW)
// with the ~28us serial 8-hop chain replaced by PARALLEL lookback:
//  - each thread folds its 16 chunk tables into one block map (registers)
//  - publishes the map IMMEDIATELY (no wait before publish)
//  - gathers all <=7 predecessor maps with batched loads (one latency,
//    retry only invalid) -- R3's mistake was polling them sequentially
//  - entry = walk e through <=7 nibble lookups
// msg: u32 per (b,pg,chain); bit31 clear = valid; poison 0xAA = invalid.
#define BB 32
#define TT 4096
#define NNV 64        // float4 groups per row (N=256)
#define CC 32         // steps per chunk (one u32 bitmask per chain)
#define PSUB 16       // chunks per block (one per 64-lane wave)
#define PG 8          // chunk-groups per chain: T / (CC*PSUB)
#define NCH 256       // chains (N)

// Compose 6-nibble maps: h = "f then g", h[e] = g[f[e]].
__device__ __forceinline__ uint32_t comp6(uint32_t f, uint32_t g) {
    uint32_t h = 0;
    #pragma unroll
    for (int e = 0; e < 6; ++e) {
        const uint32_t fe = (f >> (4 * e)) & 0xFu;
        h |= ((g >> (4 * fe)) & 0xFu) << (4 * e);
    }
    return h;
}

// Per-chunk entry->exit table from a 32-step sign bitmask.
// <=6 spikes per 32 steps (each advances na by 6): 6 branchless ctz iters.
__device__ __forceinline__ uint32_t tbl_from_mask(uint32_t m) {
    uint32_t tbl = 0;
    #pragma unroll
    for (int e = 0; e < 6; ++e) {
        int na = e;
        #pragma unroll
        for (int it = 0; it < 6; ++it) {
            const uint32_t r = (na < 32) ? (m >> na) : 0u;
            const int t = na + (r ? __builtin_ctz(r) : 0);
            na = r ? (t + 6) : na;
        }
        const int q = na > CC ? na - CC : 0;   // exit state in [0,5]
        tbl |= (uint32_t)q << (4 * e);
    }
    return tbl;
}

__global__ __launch_bounds__(1024, 4) void refrac_fused(const float* __restrict__ x,
                                                        float* __restrict__ z,
                                                        uint32_t* __restrict__ msg) {
    const int tid = threadIdx.x;
    const int pg = blockIdx.x >> 5;   // chunk-group
    const int b  = blockIdx.x & 31;   // batch
    const int psub = tid >> 6;        // which of the 16 chunks (== wave id)
    const int n4 = tid & 63;          // float4 group along N
    const int p = pg * PSUB + psub;   // absolute chunk index

    const float4* __restrict__ xv = reinterpret_cast<const float4*>(x)
        + ((size_t)b * TT + (size_t)p * CC) * NNV + n4;

    // --- Phase 1: load + sign-bit extraction (contiguous 1 KB per wave) ---
    uint32_t cur[4] = {0u, 0u, 0u, 0u};
    #pragma unroll
    for (int jb = 0; jb < CC; jb += 8) {
        float4 buf[8];
        #pragma unroll
        for (int u = 0; u < 8; ++u)
            buf[u] = xv[(size_t)(jb + u) * NNV];
        #pragma unroll
        for (int u = 0; u < 8; ++u) {
            const int j = jb + u;
            cur[0] |= (buf[u].x > 0.0f) ? (1u << j) : 0u;
            cur[1] |= (buf[u].y > 0.0f) ? (1u << j) : 0u;
            cur[2] |= (buf[u].z > 0.0f) ? (1u << j) : 0u;
            cur[3] |= (buf[u].w > 0.0f) ? (1u << j) : 0u;
        }
    }

    __shared__ uint32_t tbl_lds[PSUB][NCH];  // 16 KB: 6 nibbles per chain
    __shared__ uint8_t  ent_lds[PSUB][NCH];  //  4 KB: resolved entry states

    #pragma unroll
    for (int c = 0; c < 4; ++c)
        tbl_lds[psub][n4 * 4 + c] = tbl_from_mask(cur[c]);
    __syncthreads();

    // --- Phase 2 (tid<256, thread n == chain n): parallel lookback ---
    if (tid < NCH) {
        const int n = tid;
        uint32_t t16[PSUB];                    // chunk tables in registers
        #pragma unroll
        for (int s = 0; s < PSUB; ++s) t16[s] = tbl_lds[s][n];

        // Fold into this block's entry->exit map; publish with NO wait.
        if (pg < PG - 1) {
            uint32_t map = t16[0];
            #pragma unroll
            for (int s = 1; s < PSUB; ++s) map = comp6(map, t16[s]);
            __hip_atomic_store(msg + (((size_t)b * PG + pg) << 8) + n, map,
                               __ATOMIC_RELAXED, __HIP_MEMORY_SCOPE_AGENT);
        }

        // Gather all predecessor maps: batched loads, one latency for all,
        // retry only the ones still poisoned (bit31 set).
        uint32_t mv[PG - 1];
        #pragma unroll
        for (int g = 0; g < PG - 1; ++g) mv[g] = 0x80000000u;
        if (pg > 0) {
            const uint32_t* base = msg + (((size_t)b * PG) << 8) + n;
            for (;;) {
                bool ok = true;
                #pragma unroll
                for (int g = 0; g < PG - 1; ++g) {
                    if (g < pg && (mv[g] & 0x80000000u)) {
                        mv[g] = __hip_atomic_load(base + ((size_t)g << 8),
                                                  __ATOMIC_RELAXED,
                                                  __HIP_MEMORY_SCOPE_AGENT);
                        ok &= !(mv[g] & 0x80000000u);
                    }
                }
                if (ok) break;
                __builtin_amdgcn_s_sleep(1);
            }
        }

        // Entry = 0 walked through predecessor maps (<=7 nibble lookups).
        int e = 0;
        #pragma unroll
        for (int g = 0; g < PG - 1; ++g)
            if (g < pg) e = (int)((mv[g] >> (4 * e)) & 0xFu);

        // Walk entry through this block's 16 chunks (registers only).
        #pragma unroll
        for (int s = 0; s < PSUB; ++s) {
            ent_lds[s][n] = (uint8_t)e;
            e = (int)((t16[s] >> (4 * e)) & 0xFu);
        }
    }
    __syncthreads();

    // --- Phase 3: emit z (contiguous 1 KB per wave, plain stores) ---
    float4* __restrict__ zv = reinterpret_cast<float4*>(z)
        + ((size_t)b * TT + (size_t)p * CC) * NNV + n4;

    const uint32_t e4 = *reinterpret_cast<const uint32_t*>(&ent_lds[psub][n4 * 4]);
    uint32_t spk[4];
    #pragma unroll
    for (int c = 0; c < 4; ++c) {
        const uint32_t m = cur[c];
        int na = (int)((e4 >> (8 * c)) & 0xFFu);
        uint32_t s = 0;
        #pragma unroll
        for (int it = 0; it < 6; ++it) {
            const uint32_t r = (na < 32) ? (m >> na) : 0u;
            const int t = na + (r ? __builtin_ctz(r) : 0);
            s |= r ? (1u << (t & 31)) : 0u;   // t < 32 whenever r != 0
            na = r ? (t + 6) : na;
        }
        spk[c] = s;
    }

    #pragma unroll
    for (int j = 0; j < CC; ++j) {
        float4 o;
        o.x = ((spk[0] >> j) & 1u) ? 1.0f : 0.0f;
        o.y = ((spk[1] >> j) & 1u) ? 1.0f : 0.0f;
        o.z = ((spk[2] >> j) & 1u) ? 1.0f : 0.0f;
        o.w = ((spk[3] >> j) & 1u) ? 1.0f : 0.0f;
        zv[(size_t)j * NNV] = o;
    }
}

extern "C" void kernel_launch(void* const* d_in, const int* in_sizes, int n_in,
                              void* d_out, int out_size, void* d_ws, size_t ws_size,
                              hipStream_t stream) {
    const float* x = (const float*)d_in[0];
    float* z = (float*)d_out;
    uint32_t* msg = (uint32_t*)d_ws;

    // Deterministic "not ready" poison (0xAA => bit31 set in every word).
    hipMemsetAsync(d_ws, 0xAA, (size_t)BB * PG * NCH * sizeof(uint32_t), stream);

    refrac_fused<<<dim3(BB * PG), 1024, 0, stream>>>(x, z, msg);
}